// Round 3
// baseline (116.985 us; speedup 1.0000x reference)
//
#include <hip/hip_runtime.h>
#include <math.h>
#include <stdint.h>

typedef unsigned long long u64;
typedef unsigned int u32;

#define NCLS 80
#define NA   8400
#define NB   16
#define PRE_K 1000
#define M_FAST 256     // top-M sub-problem solved in LDS; fallback if <100 kept
#define CHUNKS 17      // decode chunks per batch (17*256 pairs >= 4200)
#define MAGIC  0x13579BDF2468ACE1ull   // flag value; non-repeating bytes (poison-safe)

// ---------------- ws layout (bytes) ----------------
// f_keys : u64   [NB][NA]        @ 0         (1,075,200)
// boxes  : float4[NB][NA]        @ 1,075,200 (2,150,400)
// flags  : u64   [NB][CHUNKS]    @ 3,225,600 (2,176)
// (labels array removed: label is packed into key low bits:
//  low32 = ~((a<<7)|label). For equal scores, ordering by low32 desc ==
//  anchor index asc (label bits sit below the anchor bits), matching the
//  reference tie rule exactly.)

// ------------------------------------------------------------------
// ONE kernel, ONE launch. Grid (1+CHUNKS, NB) x 1024.
//  blockIdx.x in [1,17]: decode chunk (x-1) of batch y.
//    256 pairs x 4 class-quarters; each quarter = 4 waves reading
//    2 KB contiguous per class-row. Release handoff: stores ->
//    __syncthreads (drains vmcnt) -> threadfence -> magic flag.
//  blockIdx.x == 0: post block for batch y. Spins on the 17 flags
//    (s_sleep), acquire-fence, then: exact top-1000 selection ->
//    top-256 IoU in LDS -> fixpoint NMS -> output. Fallback (<100
//    kept in top-256): exact full-1000 NMS, as previously verified.
// Deadlock-free: post blocks (16) never exceed CU count; decode
// blocks never wait on anything and retire, draining the queue.
// Stale-magic safe: decode is deterministic + idempotent, so even if
// flags survive from a previous identical iteration, any mixture of
// old/new f_keys/boxes bytes is the same bytes.
// ------------------------------------------------------------------
__global__ __launch_bounds__(1024) void k_fused(
    const float* __restrict__ cls0, const float* __restrict__ cls1,
    const float* __restrict__ cls2, const float* __restrict__ box0,
    const float* __restrict__ box1, const float* __restrict__ box2,
    u64* __restrict__ f_keys, float4* __restrict__ boxes,
    u64* __restrict__ flags, float* __restrict__ out)
{
    __shared__ __align__(16) char shm[65536];
    __shared__ __align__(16) u64 cbs[1024];      // candidate keys (rank-ordered)
    __shared__ u32 wtot[16];
    __shared__ u32 s_total, s_B, s_kept;
    int tid = threadIdx.x, lane = tid & 63, wv = tid >> 6;
    int b = blockIdx.y;

    // ======================= DECODE BLOCKS =======================
    if (blockIdx.x != 0) {
        int c  = blockIdx.x - 1;          // chunk 0..16
        int t  = tid & 255;               // pair slot
        int q  = tid >> 8;                // class quarter
        int pa = c * 256 + t;             // pair index in batch
        bool act = pa < 4200;

        float* pm0 = (float*)shm;                  // [3][256]
        float* pm1 = (float*)(shm + 3072);
        int*   pl0 = (int*)(shm + 6144);
        int*   pl1 = (int*)(shm + 9216);

        const float *clsp = cls0, *boxp = box0;
        int Wd = 80, ss = 8, HW = 6400, hw = 0;
        float m0 = -1e30f, m1 = -1e30f;
        int lab0 = q * 20, lab1 = q * 20;

        if (act) {
            if (pa < 3200)      { clsp = cls0; boxp = box0; Wd = 80; ss = 8;  HW = 6400; hw = 2 * pa; }
            else if (pa < 4000) { clsp = cls1; boxp = box1; Wd = 40; ss = 16; HW = 1600; hw = 2 * pa - 6400; }
            else                { clsp = cls2; boxp = box2; Wd = 20; ss = 32; HW = 400;  hw = 2 * pa - 8000; }

            const float* cp = clsp + (size_t)b * NCLS * HW + (size_t)(q * 20) * HW + hw;
            float2 v = *(const float2*)cp;
            m0 = v.x; m1 = v.y;
#pragma unroll 5
            for (int c2 = 1; c2 < 20; ++c2) {
                float2 vv = *(const float2*)(cp + (size_t)c2 * HW);
                if (vv.x > m0) { m0 = vv.x; lab0 = q * 20 + c2; }  // strict >
                if (vv.y > m1) { m1 = vv.y; lab1 = q * 20 + c2; }
            }
            if (q > 0) {
                pm0[(q - 1) * 256 + t] = m0; pl0[(q - 1) * 256 + t] = lab0;
                pm1[(q - 1) * 256 + t] = m1; pl1[(q - 1) * 256 + t] = lab1;
            }
        }
        __syncthreads();
        if (act) {
            int a = 2 * pa;
            if (q == 0) {
                // merge quarters ascending (strict > keeps lowest class index)
#pragma unroll
                for (int k = 0; k < 3; ++k) {
                    float a0 = pm0[k * 256 + t]; if (a0 > m0) { m0 = a0; lab0 = pl0[k * 256 + t]; }
                    float a1 = pm1[k * 256 + t]; if (a1 > m1) { m1 = a1; lab1 = pl1[k * 256 + t]; }
                }
                double e0 = exp(-(double)m0), e1 = exp(-(double)m1);
                float sc0 = (float)(1.0 / (1.0 + e0));
                float sc1 = (float)(1.0 / (1.0 + e1));
                float sz0 = (sc0 > 0.25f) ? sc0 : 0.0f;
                float sz1 = (sc1 > 0.25f) ? sc1 : 0.0f;
                u32 lo0 = ~(((u32)a << 7) | (u32)lab0);
                u32 lo1 = ~((((u32)(a + 1)) << 7) | (u32)lab1);
                u64* fkp = f_keys + (size_t)b * NA + a;
                fkp[0] = ((u64)__float_as_uint(sz0) << 32) | (u64)lo0;
                fkp[1] = ((u64)__float_as_uint(sz1) << 32) | (u64)lo1;
            } else if (q == 1) {
                const float* bp = boxp + (size_t)b * 4 * HW + hw;
                float fs = (float)ss;
                float2 q0v = *(const float2*)(bp);
                float2 q1v = *(const float2*)(bp + HW);
                float2 q2v = *(const float2*)(bp + 2 * HW);
                float2 q3v = *(const float2*)(bp + 3 * HW);
                float px = (float)((hw % Wd) * ss);
                float py = (float)((hw / Wd) * ss);
                float px1 = px + fs;              // exact: small ints in float
                boxes[(size_t)b * NA + a]     = make_float4(px  - q0v.x * fs, py - q1v.x * fs, px  + q2v.x * fs, py + q3v.x * fs);
                boxes[(size_t)b * NA + a + 1] = make_float4(px1 - q0v.y * fs, py - q1v.y * fs, px1 + q2v.y * fs, py + q3v.y * fs);
            }
        }
        __syncthreads();   // drains vmcnt: all block stores complete
        if (tid == 0) {
            __threadfence();
            __hip_atomic_store(&flags[b * CHUNKS + c], MAGIC,
                               __ATOMIC_RELAXED, __HIP_MEMORY_SCOPE_AGENT);
        }
        return;
    }

    // ======================= POST BLOCK (x==0) =======================
    if (tid == 0) {
        for (int i = 0; i < CHUNKS; ++i) {
            while (__hip_atomic_load(&flags[b * CHUNKS + i],
                                     __ATOMIC_RELAXED, __HIP_MEMORY_SCOPE_AGENT) != MAGIC)
                __builtin_amdgcn_s_sleep(8);
        }
        __threadfence();   // acquire
    }
    __syncthreads();

    const u64* fk = f_keys + (size_t)b * NA;

    // stage keys once: fk read exactly one time from global
    u64 kr[9];
#pragma unroll
    for (int k = 0; k < 9; ++k) {
        int i = tid + k * 1024;
        kr[k] = (i < NA) ? fk[i] : 0ull;
    }

    // ================= Selection (exact top-1000 ranks) =================
    {
        u32* R  = (u32*)shm;                 // 4096 u32: histogram -> suffix counts
        u32* C  = (u32*)(shm + 16384);       // 4096 u32: bucket-fill counters
        u64* BK = (u64*)(shm + 32768);       // 4096 bucket slots (32 KB)

        for (int i = tid; i < 4096; i += 1024) { R[i] = 0; C[i] = 0; }
        __syncthreads();

        // 1. histogram over score bits (from regs)
#pragma unroll
        for (int k = 0; k < 9; ++k) {
            u32 sb = (u32)(kr[k] >> 32);
            if (sb) {
                int bin = (int)(sb >> 12) - 0x3E800;
                bin = max(0, min(bin, 4095));
                atomicAdd(&R[bin], 1u);
            }
        }
        __syncthreads();

        // 2. in-place suffix-sum: R[bin] = #keys in bins >= bin
        u32 h0 = R[4*tid], h1 = R[4*tid+1], h2 = R[4*tid+2], h3 = R[4*tid+3];
        u32 g = h0 + h1 + h2 + h3;
        u32 S = g;
#pragma unroll
        for (int off = 1; off < 64; off <<= 1) {
            u32 x = __shfl_down(S, off, 64);
            if (lane + off < 64) S += x;          // suffix-incl over lanes
        }
        if (lane == 0) wtot[wv] = S;
        __syncthreads();
        u32 wsuf = 0;
#pragma unroll
        for (int w = 0; w < 16; ++w) if (w > wv) wsuf += wtot[w];
        u32 above = (S - g) + wsuf;               // keys in bins > 4*tid+3
        u32 r3 = h3 + above, r2 = h2 + r3, r1 = h1 + r2, r0 = h0 + r1;
        R[4*tid] = r0; R[4*tid+1] = r1; R[4*tid+2] = r2; R[4*tid+3] = r3;
        if (tid == 0) s_total = 0;
        __syncthreads();
        if (tid == 0) s_total = R[0];
        __syncthreads();
        u32 total = s_total;

        // 3. threshold bin B (unique writer; B=0 if total<1000)
        if (tid == 0 && total < PRE_K) s_B = 0;
#pragma unroll
        for (int k = 0; k < 4; ++k) {
            int bin = 4*tid + k;
            u32 Rb = R[bin];
            u32 Rn = (bin < 4095) ? R[bin + 1] : 0;
            if (Rb >= PRE_K && Rn < PRE_K) s_B = (u32)bin;
        }
        __syncthreads();
        u32 B = s_B;
        u32 Cv = R[B];                            // survivors (bins >= B)

        if (Cv <= 4096) {
            // 4. bucket-place survivors at exact rank-base (from regs)
#pragma unroll
            for (int k = 0; k < 9; ++k) {
                u64 key = kr[k];
                u32 sb = (u32)(key >> 32);
                if (sb) {
                    int bin = (int)(sb >> 12) - 0x3E800;
                    bin = max(0, min(bin, 4095));
                    if ((u32)bin >= B) {
                        u32 base = (bin < 4095) ? R[bin + 1] : 0;
                        u32 off = atomicAdd(&C[bin], 1u);
                        BK[base + off] = key;
                    }
                }
            }
            __syncthreads();
            // 5. exact rank = bucket base + #{same-bin keys greater}
            for (int s2 = tid; s2 < (int)Cv; s2 += 1024) {
                u64 key = BK[s2];
                u32 sb = (u32)(key >> 32);
                int bin = (int)(sb >> 12) - 0x3E800;
                bin = max(0, min(bin, 4095));
                u32 base = (bin < 4095) ? R[bin + 1] : 0;
                u32 n = R[bin] - base;
                u32 cnt = 0;
                for (u32 j = 0; j < n; ++j) cnt += (BK[base + j] > key) ? 1u : 0u;
                u32 rank = base + cnt;
                if (rank < PRE_K) cbs[rank] = key;
            }
        } else {
            // fallback (pathological bin collisions): exact rank via global
            for (int i = tid; i < NA; i += 1024) {
                u64 key = fk[i];
                u32 sb = (u32)(key >> 32);
                if (!sb) continue;
                int bin = (int)(sb >> 12) - 0x3E800;
                bin = max(0, min(bin, 4095));
                if ((u32)bin < B) continue;
                u32 rank = 0;
                for (int j = 0; j < NA; ++j) rank += (fk[j] > key) ? 1u : 0u;
                if (rank < PRE_K) cbs[rank] = key;
            }
        }
        // 6. zero-score backfill (anchor t2, label 0; ties by index asc)
        for (int t2 = tid; (int)total + t2 < PRE_K; t2 += 1024)
            cbs[total + t2] = (u64)(u32)~((u32)t2 << 7);
        __syncthreads();   // cbs complete; R/C/BK dead from here on
    }

    // ================= Phase B LDS layout (reuses shm) =================
    float4* sbox = (float4*)shm;                 // 1000 x 16 B        [    0..16384)
    float*  sar  = (float*)(shm + 16384);        // 1000 x 4 B         [16384..20480)
    u64*    mk   = (u64*)(shm + 20480);          // 256 rows x 4 words [20480..28672)
    u64*    Ksh  = (u64*)(shm + 28672);          // [2][16] ping-pong  [28672..28928)
    int*    chgA = (int*)(shm + 28928);          // 32 change flags    [28928..29056)

    // publish top-256 only (fast path working set); fallback adds the rest
    if (tid < M_FAST) {
        u64 key = cbs[tid];
        u32 v = ~(u32)key;
        u32 a = v >> 7;
        float4 bx = boxes[(size_t)b * NA + a];
        float off = (float)(v & 127u) * 8192.0f;  // exact mult
        float x1 = bx.x + off, y1 = bx.y + off, x2 = bx.z + off, y2 = bx.w + off;
        sbox[tid] = make_float4(x1, y1, x2, y2);
        float w = fmaxf(__fsub_rn(x2, x1), 0.0f);
        float h = fmaxf(__fsub_rn(y2, y1), 0.0f);
        sar[tid] = __fmul_rn(w, h);
    }
    __syncthreads();

    // ================= IoU lower-tri for top-256, into LDS =================
    {
        int i = tid & 255, w = tid >> 8;         // tid == w*256+i covers all (i,w)
        u64 bits = 0;
        int iw = i >> 6;
        if (w <= iw) {
            int jmax = (w < iw) ? 64 : (i & 63); // strictly j < i
            float4 A = sbox[i];
            float aar = sar[i];
            const float4* bj = sbox + w * 64;
            const float*  aj = sar  + w * 64;
            for (int jj = 0; jj < jmax; ++jj) {
                float4 Bx = bj[jj];              // ds_read_b128 broadcast
                float sab = aj[jj];
                float lx = fmaxf(A.x, Bx.x), ly = fmaxf(A.y, Bx.y);
                float rx = fminf(A.z, Bx.z), ry = fminf(A.w, Bx.w);
                float ww = fmaxf(__fsub_rn(rx, lx), 0.0f);
                float hh = fmaxf(__fsub_rn(ry, ly), 0.0f);
                float inter = __fmul_rn(ww, hh);
                float uni = __fsub_rn(__fadd_rn(aar, sab), inter);
                // iou>0.65 <=> inter > 0.65*max(uni,1e-6)  (division-free)
                if (inter > 0.65f * fmaxf(uni, 1e-6f)) bits |= (1ull << jj);
            }
        }
        mk[i * 4 + w] = bits;                    // rows pre-masked by construction
    }
    __syncthreads();

    // ================= Fixpoint NMS over top-256 (LDS) =================
    bool inr = tid < M_FAST;
    u64 key = (tid < PRE_K) ? cbs[tid] : 0ull;
    bool valid = inr && ((u32)(key >> 32) != 0u);
    u64 rowm4[4];
#pragma unroll
    for (int k = 0; k < 4; ++k) rowm4[k] = inr ? mk[tid * 4 + k] : 0ull;

    u64 v0 = __ballot(valid);
    if (inr && lane == 0) Ksh[wv] = v0;          // slots of 4 words, wv in 0..3
    if (tid < 32) chgA[tid] = 0;
    __syncthreads();

    int fin = 0;
    for (int it = 0; it < M_FAST + 2; ++it) {
        int p = it & 1;
        const u64* Kc = Ksh + p * 4;
        u64 kold = inr ? Kc[wv] : 0ull;
        u64 acc = 0;
#pragma unroll
        for (int k = 0; k < 4; ++k) acc |= rowm4[k] & Kc[k];
        bool kept = valid && (acc == 0ull);
        u64 nk = __ballot(kept);
        if (inr && lane == 0) {
            Ksh[(p ^ 1) * 4 + wv] = nk;
            if (nk != kold) chgA[it & 31] = 1;
        }
        __syncthreads();
        fin = p ^ 1;
        if (chgA[it & 31] == 0) break;           // fixpoint certified
        if ((it & 31) == 31) {                   // recycle flag slots (rare)
            __syncthreads();
            if (tid < 32) chgA[tid] = 0;
            __syncthreads();
        }
    }
    const u64* Kf = Ksh + fin * 4;
    if (tid == 0) {
        u32 kt = 0;
#pragma unroll
        for (int k = 0; k < 4; ++k) kt += __popcll(Kf[k]);
        s_kept = kt;
    }
    __syncthreads();

    if (s_kept >= 100) {
        // All 100 output rows are kept candidates inside the top-256.
        if (inr) {
            bool kept = (Kf[wv] >> lane) & 1ull;
            u64 low = (1ull << lane) - 1ull;
            int pc = 0;
#pragma unroll
            for (int k = 0; k < 4; ++k) {
                u64 lt = (k < wv) ? ~0ull : ((k == wv) ? low : 0ull);
                pc += __popcll(Kf[k] & lt);
            }
            if (kept && pc < 100) {
                u32 v = ~(u32)key;
                u32 a = v >> 7;
                float4 bx = boxes[(size_t)b * NA + a];
                float fsc = __uint_as_float((u32)(key >> 32));
                float* dr = out + (size_t)(b * 100 + pc) * 5;
                dr[0] = bx.x; dr[1] = bx.y; dr[2] = bx.z; dr[3] = bx.w; dr[4] = fsc;
                out[(size_t)NB * 100 * 5 + b * 100 + pc] = (float)(v & 127u);
            }
        }
        return;                                  // uniform: s_kept is shared
    }

    // ================= Fallback: exact full-1000 NMS (rare) =================
    {
        // publish the remaining candidates' boxes/areas
        if (tid >= M_FAST && tid < PRE_K) {
            u64 kk = cbs[tid];
            u32 v = ~(u32)kk;
            u32 a = v >> 7;
            float4 bx = boxes[(size_t)b * NA + a];
            float off = (float)(v & 127u) * 8192.0f;
            float x1 = bx.x + off, y1 = bx.y + off, x2 = bx.z + off, y2 = bx.w + off;
            sbox[tid] = make_float4(x1, y1, x2, y2);
            float w = fmaxf(__fsub_rn(x2, x1), 0.0f);
            float h = fmaxf(__fsub_rn(y2, y1), 0.0f);
            sar[tid] = __fmul_rn(w, h);
        }
        __syncthreads();

        bool inrF = tid < PRE_K;
        u64 rowm[16];
#pragma unroll
        for (int k = 0; k < 16; ++k) rowm[k] = 0ull;
        if (inrF) {
            float4 A = sbox[tid];
            float aar = sar[tid];
            for (int k = 0; k <= wv; ++k) {      // row tid: words 0..tid>>6
                int jmax = (k < wv) ? 64 : lane; // strictly j < tid
                const float4* bj = sbox + k * 64;
                const float*  aj = sar  + k * 64;
                u64 bits = 0;
                for (int jj = 0; jj < jmax; ++jj) {
                    float4 Bx = bj[jj];
                    float sab = aj[jj];
                    float lx = fmaxf(A.x, Bx.x), ly = fmaxf(A.y, Bx.y);
                    float rx = fminf(A.z, Bx.z), ry = fminf(A.w, Bx.w);
                    float ww = fmaxf(__fsub_rn(rx, lx), 0.0f);
                    float hh = fmaxf(__fsub_rn(ry, ly), 0.0f);
                    float inter = __fmul_rn(ww, hh);
                    float uni = __fsub_rn(__fadd_rn(aar, sab), inter);
                    if (inter > 0.65f * fmaxf(uni, 1e-6f)) bits |= (1ull << jj);
                }
                rowm[k] = bits;
            }
        }
        bool valid2 = inrF && ((u32)(key >> 32) != 0u);

        u64 vF = __ballot(valid2);
        if (lane == 0) Ksh[wv] = vF;             // slots of 16 words now
        if (tid < 32) chgA[tid] = 0;
        __syncthreads();

        int finF = 0;
        for (int it = 0; it < PRE_K + 2; ++it) {
            int p = it & 1;
            const u64* Kc = Ksh + p * 16;
            u64 kold = Kc[wv];
            u64 acc = 0;
#pragma unroll
            for (int k = 0; k < 16; ++k) acc |= rowm[k] & Kc[k];
            bool kept = valid2 && (acc == 0ull);
            u64 nk = __ballot(kept);
            if (lane == 0) {
                Ksh[(p ^ 1) * 16 + wv] = nk;
                if (nk != kold) chgA[it & 31] = 1;
            }
            __syncthreads();
            finF = p ^ 1;
            if (chgA[it & 31] == 0) break;
            if ((it & 31) == 31) {
                __syncthreads();
                if (tid < 32) chgA[tid] = 0;
                __syncthreads();
            }
        }
        const u64* Kf2 = Ksh + finF * 16;

        // epilogue: rank kept (by index) then zero-score backfill (by index)
        u64 low = (1ull << lane) - 1ull;
        int pc = 0, Kt = 0;
#pragma unroll
        for (int k = 0; k < 16; ++k) {
            u64 kk = Kf2[k];
            u64 lt = (k < wv) ? ~0ull : ((k == wv) ? low : 0ull);
            pc += __popcll(kk & lt);
            Kt += __popcll(kk);
        }
        if (inrF) {
            bool kept = (Kf2[wv] >> lane) & 1ull;
            int row = kept ? pc : (Kt + (tid - pc));
            if (row < 100) {
                u32 v = ~(u32)key;
                u32 a = v >> 7;
                float4 bx = boxes[(size_t)b * NA + a];
                float fsc = kept ? __uint_as_float((u32)(key >> 32)) : 0.0f;
                float* dr = out + (size_t)(b * 100 + row) * 5;
                dr[0] = bx.x; dr[1] = bx.y; dr[2] = bx.z; dr[3] = bx.w; dr[4] = fsc;
                out[(size_t)NB * 100 * 5 + b * 100 + row] = (float)(v & 127u);
            }
        }
    }
}

extern "C" void kernel_launch(void* const* d_in, const int* in_sizes, int n_in,
                              void* d_out, int out_size, void* d_ws, size_t ws_size,
                              hipStream_t stream) {
    const float* cls0 = (const float*)d_in[0];
    const float* cls1 = (const float*)d_in[1];
    const float* cls2 = (const float*)d_in[2];
    const float* box0 = (const float*)d_in[3];
    const float* box1 = (const float*)d_in[4];
    const float* box2 = (const float*)d_in[5];
    float* out = (float*)d_out;

    char* w = (char*)d_ws;
    u64*    f_keys = (u64*)(w);
    float4* boxes  = (float4*)(w + 1075200);
    u64*    flags  = (u64*)(w + 3225600);

    k_fused<<<dim3(1 + CHUNKS, NB), 1024, 0, stream>>>(
        cls0, cls1, cls2, box0, box1, box2, f_keys, boxes, flags, out);
}

// Round 4
// 105.175 us; speedup vs baseline: 1.1123x; 1.1123x over previous
//
#include <hip/hip_runtime.h>
#include <math.h>
#include <stdint.h>

typedef unsigned long long u64;
typedef unsigned int u32;

#define NCLS 80
#define NA   8400
#define NB   16
#define PRE_K 1000
#define M_FAST 256   // top-M sub-problem solved in LDS; fallback if <100 kept

// ---------------- ws layout (bytes) ----------------
// f_keys : u64   [NB][NA]        @ 0         (1,075,200)
// boxes  : float4[NB][NA]        @ 1,075,200 (2,150,400)
// (labels packed into key low bits: low32 = ~((a<<7)|label). For equal
//  scores, low32 desc == anchor index asc (label bits below anchor bits),
//  matching the reference tie rule exactly. Verified exact in R3.)

// ------------------------------------------------------------------
// Kernel 1: decode, float4 class loads (4 anchors/lane).
// R3 post-mortem: decode is latency-bound (VALUBusy 4%, HBM 7%), not
// BW-bound. Lever = more bytes in flight + more waves/CU. Each wave
// owns one class-quarter (20 classes, fully unrolled float4 loads =
// 20 x 1KB wave-loads in flight); block = 4 waves x 256 anchors.
// Grid 33x16 = 528 blocks -> ~4 blocks/CU. Wave 0 merges quarters
// (ascending order, strict '>' == argmax first-index ties) + sigmoid
// + key store; wave 1 decodes boxes (independent, runs concurrently).
// ------------------------------------------------------------------
__global__ __launch_bounds__(256) void k_decode(
    const float* __restrict__ cls0, const float* __restrict__ cls1,
    const float* __restrict__ cls2, const float* __restrict__ box0,
    const float* __restrict__ box1, const float* __restrict__ box2,
    u64* __restrict__ f_keys, float4* __restrict__ boxes)
{
    __shared__ float4 pmx[3][64];
    __shared__ int4   plb[3][64];

    int l  = threadIdx.x & 63;        // lane
    int w  = threadIdx.x >> 6;        // class quarter / role wave
    int b  = blockIdx.y;
    int a0 = blockIdx.x * 256 + 4 * l;   // first of 4 anchors for this lane
    bool act = a0 < NA;               // quads are 4-aligned; levels are too

    // per-lane level select (block 31 straddles the 8000 boundary)
    const float *clsp = cls0, *boxp = box0;
    int Wd = 80, ss = 8, HW = 6400, hw0 = 0;
    if (act) {
        if (a0 < 6400)      { clsp = cls0; boxp = box0; Wd = 80; ss = 8;  HW = 6400; hw0 = a0; }
        else if (a0 < 8000) { clsp = cls1; boxp = box1; Wd = 40; ss = 16; HW = 1600; hw0 = a0 - 6400; }
        else                { clsp = cls2; boxp = box2; Wd = 20; ss = 32; HW = 400;  hw0 = a0 - 8000; }
    }

    float4 mx = make_float4(-1e30f, -1e30f, -1e30f, -1e30f);
    int4   lb = make_int4(w * 20, w * 20, w * 20, w * 20);

    if (act) {
        const float* cp = clsp + (size_t)b * NCLS * HW + (size_t)(w * 20) * HW + hw0;
        mx = *(const float4*)cp;
#pragma unroll
        for (int c = 1; c < 20; ++c) {
            float4 v = *(const float4*)(cp + (size_t)c * HW);
            if (v.x > mx.x) { mx.x = v.x; lb.x = w * 20 + c; }   // strict >
            if (v.y > mx.y) { mx.y = v.y; lb.y = w * 20 + c; }
            if (v.z > mx.z) { mx.z = v.z; lb.z = w * 20 + c; }
            if (v.w > mx.w) { mx.w = v.w; lb.w = w * 20 + c; }
        }
        if (w > 0) { pmx[w - 1][l] = mx; plb[w - 1][l] = lb; }
    }
    __syncthreads();
    if (!act) return;

    if (w == 0) {
        // merge quarters ascending (strict > keeps lowest class index)
#pragma unroll
        for (int k = 0; k < 3; ++k) {
            float4 o = pmx[k][l]; int4 ol = plb[k][l];
            if (o.x > mx.x) { mx.x = o.x; lb.x = ol.x; }
            if (o.y > mx.y) { mx.y = o.y; lb.y = ol.y; }
            if (o.z > mx.z) { mx.z = o.z; lb.z = ol.z; }
            if (o.w > mx.w) { mx.w = o.w; lb.w = ol.w; }
        }
        float mv[4] = {mx.x, mx.y, mx.z, mx.w};
        int   lv[4] = {lb.x, lb.y, lb.z, lb.w};
        u64 kk[4];
#pragma unroll
        for (int j = 0; j < 4; ++j) {
            double e = exp(-(double)mv[j]);
            float sc = (float)(1.0 / (1.0 + e));
            float sz = (sc > 0.25f) ? sc : 0.0f;
            u32 lo = ~((((u32)(a0 + j)) << 7) | (u32)lv[j]);
            kk[j] = ((u64)__float_as_uint(sz) << 32) | (u64)lo;
        }
        u64* fkp = f_keys + (size_t)b * NA + a0;   // 32B-aligned (a0 % 4 == 0)
        *(ulonglong2*)(fkp)     = make_ulonglong2(kk[0], kk[1]);
        *(ulonglong2*)(fkp + 2) = make_ulonglong2(kk[2], kk[3]);
    } else if (w == 1) {
        // box decode: 4 anchors/lane, float4 loads per dist-row
        const float* bp = boxp + (size_t)b * 4 * HW + hw0;
        float fs = (float)ss;
        float4 d0 = *(const float4*)(bp);
        float4 d1 = *(const float4*)(bp + HW);
        float4 d2 = *(const float4*)(bp + 2 * HW);
        float4 d3 = *(const float4*)(bp + 3 * HW);
        int qx = hw0 % Wd, qy = hw0 / Wd;
        float4* bo = boxes + (size_t)b * NA + a0;
        float l0[4] = {d0.x, d0.y, d0.z, d0.w};
        float t0[4] = {d1.x, d1.y, d1.z, d1.w};
        float r0[4] = {d2.x, d2.y, d2.z, d2.w};
        float b0[4] = {d3.x, d3.y, d3.z, d3.w};
#pragma unroll
        for (int j = 0; j < 4; ++j) {
            float px = (float)(qx * ss);           // exact: small ints in float
            float py = (float)(qy * ss);
            bo[j] = make_float4(px - l0[j] * fs, py - t0[j] * fs,
                                px + r0[j] * fs, py + b0[j] * fs);
            ++qx; if (qx == Wd) { qx = 0; ++qy; }
        }
    }
}

// ------------------------------------------------------------------
// Kernel 2: ONE block per batch (proven in R1-R3). Selection (keys
// register-staged, single global pass) -> top-256 IoU in LDS ->
// fixpoint NMS -> output. Fallbacks: exact full-1000 NMS if <100
// kept in top-256; exact global rank if pathological bin collisions.
// ------------------------------------------------------------------
__global__ __launch_bounds__(1024, 1) void k_post(
    const u64* __restrict__ f_keys, const float4* __restrict__ boxes,
    float* __restrict__ out)
{
    __shared__ __align__(16) char shm[65536];
    __shared__ __align__(16) u64 cbs[1024];      // candidate keys (rank-ordered)
    __shared__ u32 wtot[16];
    __shared__ u32 s_total, s_B, s_kept;
    int tid = threadIdx.x, lane = tid & 63, wv = tid >> 6;
    int b = blockIdx.x;

    const u64* fk = f_keys + (size_t)b * NA;

    // stage keys once: fk read exactly one time from global
    u64 kr[9];
#pragma unroll
    for (int k = 0; k < 9; ++k) {
        int i = tid + k * 1024;
        kr[k] = (i < NA) ? fk[i] : 0ull;
    }

    // ================= Selection (exact top-1000 ranks) =================
    {
        u32* R  = (u32*)shm;                 // 4096 u32: histogram -> suffix counts
        u32* C  = (u32*)(shm + 16384);       // 4096 u32: bucket-fill counters
        u64* BK = (u64*)(shm + 32768);       // 4096 bucket slots (32 KB)

        for (int i = tid; i < 4096; i += 1024) { R[i] = 0; C[i] = 0; }
        __syncthreads();

        // 1. histogram over score bits (from regs)
#pragma unroll
        for (int k = 0; k < 9; ++k) {
            u32 sb = (u32)(kr[k] >> 32);
            if (sb) {
                int bin = (int)(sb >> 12) - 0x3E800;
                bin = max(0, min(bin, 4095));
                atomicAdd(&R[bin], 1u);
            }
        }
        __syncthreads();

        // 2. in-place suffix-sum: R[bin] = #keys in bins >= bin
        u32 h0 = R[4*tid], h1 = R[4*tid+1], h2 = R[4*tid+2], h3 = R[4*tid+3];
        u32 g = h0 + h1 + h2 + h3;
        u32 S = g;
#pragma unroll
        for (int off = 1; off < 64; off <<= 1) {
            u32 x = __shfl_down(S, off, 64);
            if (lane + off < 64) S += x;          // suffix-incl over lanes
        }
        if (lane == 0) wtot[wv] = S;
        __syncthreads();
        u32 wsuf = 0;
#pragma unroll
        for (int w = 0; w < 16; ++w) if (w > wv) wsuf += wtot[w];
        u32 above = (S - g) + wsuf;               // keys in bins > 4*tid+3
        u32 r3 = h3 + above, r2 = h2 + r3, r1 = h1 + r2, r0 = h0 + r1;
        R[4*tid] = r0; R[4*tid+1] = r1; R[4*tid+2] = r2; R[4*tid+3] = r3;
        if (tid == 0) s_total = 0;
        __syncthreads();
        if (tid == 0) s_total = R[0];
        __syncthreads();
        u32 total = s_total;

        // 3. threshold bin B (unique writer; B=0 if total<1000)
        if (tid == 0 && total < PRE_K) s_B = 0;
#pragma unroll
        for (int k = 0; k < 4; ++k) {
            int bin = 4*tid + k;
            u32 Rb = R[bin];
            u32 Rn = (bin < 4095) ? R[bin + 1] : 0;
            if (Rb >= PRE_K && Rn < PRE_K) s_B = (u32)bin;
        }
        __syncthreads();
        u32 B = s_B;
        u32 Cv = R[B];                            // survivors (bins >= B)

        if (Cv <= 4096) {
            // 4. bucket-place survivors at exact rank-base (from regs)
#pragma unroll
            for (int k = 0; k < 9; ++k) {
                u64 key = kr[k];
                u32 sb = (u32)(key >> 32);
                if (sb) {
                    int bin = (int)(sb >> 12) - 0x3E800;
                    bin = max(0, min(bin, 4095));
                    if ((u32)bin >= B) {
                        u32 base = (bin < 4095) ? R[bin + 1] : 0;
                        u32 off = atomicAdd(&C[bin], 1u);
                        BK[base + off] = key;
                    }
                }
            }
            __syncthreads();
            // 5. exact rank = bucket base + #{same-bin keys greater}
            for (int s2 = tid; s2 < (int)Cv; s2 += 1024) {
                u64 key = BK[s2];
                u32 sb = (u32)(key >> 32);
                int bin = (int)(sb >> 12) - 0x3E800;
                bin = max(0, min(bin, 4095));
                u32 base = (bin < 4095) ? R[bin + 1] : 0;
                u32 n = R[bin] - base;
                u32 cnt = 0;
                for (u32 j = 0; j < n; ++j) cnt += (BK[base + j] > key) ? 1u : 0u;
                u32 rank = base + cnt;
                if (rank < PRE_K) cbs[rank] = key;
            }
        } else {
            // fallback (pathological bin collisions): exact rank via global
            for (int i = tid; i < NA; i += 1024) {
                u64 key = fk[i];
                u32 sb = (u32)(key >> 32);
                if (!sb) continue;
                int bin = (int)(sb >> 12) - 0x3E800;
                bin = max(0, min(bin, 4095));
                if ((u32)bin < B) continue;
                u32 rank = 0;
                for (int j = 0; j < NA; ++j) rank += (fk[j] > key) ? 1u : 0u;
                if (rank < PRE_K) cbs[rank] = key;
            }
        }
        // 6. zero-score backfill (anchor t2, label 0; ties by index asc)
        for (int t2 = tid; (int)total + t2 < PRE_K; t2 += 1024)
            cbs[total + t2] = (u64)(u32)~((u32)t2 << 7);
        __syncthreads();   // cbs complete; R/C/BK dead from here on
    }

    // ================= Phase B LDS layout (reuses shm) =================
    float4* sbox = (float4*)shm;                 // 1000 x 16 B        [    0..16384)
    float*  sar  = (float*)(shm + 16384);        // 1000 x 4 B         [16384..20480)
    u64*    mk   = (u64*)(shm + 20480);          // 256 rows x 4 words [20480..28672)
    u64*    Ksh  = (u64*)(shm + 28672);          // [2][16] ping-pong  [28672..28928)
    int*    chgA = (int*)(shm + 28928);          // 32 change flags    [28928..29056)

    // publish top-256 only (fast path working set); fallback adds the rest
    if (tid < M_FAST) {
        u64 key = cbs[tid];
        u32 v = ~(u32)key;
        u32 a = v >> 7;
        float4 bx = boxes[(size_t)b * NA + a];
        float off = (float)(v & 127u) * 8192.0f;  // exact mult
        float x1 = bx.x + off, y1 = bx.y + off, x2 = bx.z + off, y2 = bx.w + off;
        sbox[tid] = make_float4(x1, y1, x2, y2);
        float w = fmaxf(__fsub_rn(x2, x1), 0.0f);
        float h = fmaxf(__fsub_rn(y2, y1), 0.0f);
        sar[tid] = __fmul_rn(w, h);
    }
    __syncthreads();

    // ================= IoU lower-tri for top-256, into LDS =================
    {
        int i = tid & 255, w = tid >> 8;         // tid == w*256+i covers all (i,w)
        u64 bits = 0;
        int iw = i >> 6;
        if (w <= iw) {
            int jmax = (w < iw) ? 64 : (i & 63); // strictly j < i
            float4 A = sbox[i];
            float aar = sar[i];
            const float4* bj = sbox + w * 64;
            const float*  aj = sar  + w * 64;
            for (int jj = 0; jj < jmax; ++jj) {
                float4 Bx = bj[jj];              // ds_read_b128 broadcast
                float sab = aj[jj];
                float lx = fmaxf(A.x, Bx.x), ly = fmaxf(A.y, Bx.y);
                float rx = fminf(A.z, Bx.z), ry = fminf(A.w, Bx.w);
                float ww = fmaxf(__fsub_rn(rx, lx), 0.0f);
                float hh = fmaxf(__fsub_rn(ry, ly), 0.0f);
                float inter = __fmul_rn(ww, hh);
                float uni = __fsub_rn(__fadd_rn(aar, sab), inter);
                // iou>0.65 <=> inter > 0.65*max(uni,1e-6)  (division-free)
                if (inter > 0.65f * fmaxf(uni, 1e-6f)) bits |= (1ull << jj);
            }
        }
        mk[i * 4 + w] = bits;                    // rows pre-masked by construction
    }
    __syncthreads();

    // ================= Fixpoint NMS over top-256 (LDS) =================
    bool inr = tid < M_FAST;
    u64 key = (tid < PRE_K) ? cbs[tid] : 0ull;
    bool valid = inr && ((u32)(key >> 32) != 0u);
    u64 rowm4[4];
#pragma unroll
    for (int k = 0; k < 4; ++k) rowm4[k] = inr ? mk[tid * 4 + k] : 0ull;

    u64 v0 = __ballot(valid);
    if (inr && lane == 0) Ksh[wv] = v0;          // slots of 4 words, wv in 0..3
    if (tid < 32) chgA[tid] = 0;
    __syncthreads();

    int fin = 0;
    for (int it = 0; it < M_FAST + 2; ++it) {
        int p = it & 1;
        const u64* Kc = Ksh + p * 4;
        u64 kold = inr ? Kc[wv] : 0ull;
        u64 acc = 0;
#pragma unroll
        for (int k = 0; k < 4; ++k) acc |= rowm4[k] & Kc[k];
        bool kept = valid && (acc == 0ull);
        u64 nk = __ballot(kept);
        if (inr && lane == 0) {
            Ksh[(p ^ 1) * 4 + wv] = nk;
            if (nk != kold) chgA[it & 31] = 1;
        }
        __syncthreads();
        fin = p ^ 1;
        if (chgA[it & 31] == 0) break;           // fixpoint certified
        if ((it & 31) == 31) {                   // recycle flag slots (rare)
            __syncthreads();
            if (tid < 32) chgA[tid] = 0;
            __syncthreads();
        }
    }
    const u64* Kf = Ksh + fin * 4;
    if (tid == 0) {
        u32 kt = 0;
#pragma unroll
        for (int k = 0; k < 4; ++k) kt += __popcll(Kf[k]);
        s_kept = kt;
    }
    __syncthreads();

    if (s_kept >= 100) {
        // All 100 output rows are kept candidates inside the top-256.
        if (inr) {
            bool kept = (Kf[wv] >> lane) & 1ull;
            u64 low = (1ull << lane) - 1ull;
            int pc = 0;
#pragma unroll
            for (int k = 0; k < 4; ++k) {
                u64 lt = (k < wv) ? ~0ull : ((k == wv) ? low : 0ull);
                pc += __popcll(Kf[k] & lt);
            }
            if (kept && pc < 100) {
                u32 v = ~(u32)key;
                u32 a = v >> 7;
                float4 bx = boxes[(size_t)b * NA + a];
                float fsc = __uint_as_float((u32)(key >> 32));
                float* dr = out + (size_t)(b * 100 + pc) * 5;
                dr[0] = bx.x; dr[1] = bx.y; dr[2] = bx.z; dr[3] = bx.w; dr[4] = fsc;
                out[(size_t)NB * 100 * 5 + b * 100 + pc] = (float)(v & 127u);
            }
        }
        return;                                  // uniform: s_kept is shared
    }

    // ================= Fallback: exact full-1000 NMS (rare) =================
    {
        // publish the remaining candidates' boxes/areas
        if (tid >= M_FAST && tid < PRE_K) {
            u64 kk = cbs[tid];
            u32 v = ~(u32)kk;
            u32 a = v >> 7;
            float4 bx = boxes[(size_t)b * NA + a];
            float off = (float)(v & 127u) * 8192.0f;
            float x1 = bx.x + off, y1 = bx.y + off, x2 = bx.z + off, y2 = bx.w + off;
            sbox[tid] = make_float4(x1, y1, x2, y2);
            float w = fmaxf(__fsub_rn(x2, x1), 0.0f);
            float h = fmaxf(__fsub_rn(y2, y1), 0.0f);
            sar[tid] = __fmul_rn(w, h);
        }
        __syncthreads();

        bool inrF = tid < PRE_K;
        u64 rowm[16];
#pragma unroll
        for (int k = 0; k < 16; ++k) rowm[k] = 0ull;
        if (inrF) {
            float4 A = sbox[tid];
            float aar = sar[tid];
            for (int k = 0; k <= wv; ++k) {      // row tid: words 0..tid>>6
                int jmax = (k < wv) ? 64 : lane; // strictly j < tid
                const float4* bj = sbox + k * 64;
                const float*  aj = sar  + k * 64;
                u64 bits = 0;
                for (int jj = 0; jj < jmax; ++jj) {
                    float4 Bx = bj[jj];
                    float sab = aj[jj];
                    float lx = fmaxf(A.x, Bx.x), ly = fmaxf(A.y, Bx.y);
                    float rx = fminf(A.z, Bx.z), ry = fminf(A.w, Bx.w);
                    float ww = fmaxf(__fsub_rn(rx, lx), 0.0f);
                    float hh = fmaxf(__fsub_rn(ry, ly), 0.0f);
                    float inter = __fmul_rn(ww, hh);
                    float uni = __fsub_rn(__fadd_rn(aar, sab), inter);
                    if (inter > 0.65f * fmaxf(uni, 1e-6f)) bits |= (1ull << jj);
                }
                rowm[k] = bits;
            }
        }
        bool valid2 = inrF && ((u32)(key >> 32) != 0u);

        u64 vF = __ballot(valid2);
        if (lane == 0) Ksh[wv] = vF;             // slots of 16 words now
        if (tid < 32) chgA[tid] = 0;
        __syncthreads();

        int finF = 0;
        for (int it = 0; it < PRE_K + 2; ++it) {
            int p = it & 1;
            const u64* Kc = Ksh + p * 16;
            u64 kold = Kc[wv];
            u64 acc = 0;
#pragma unroll
            for (int k = 0; k < 16; ++k) acc |= rowm[k] & Kc[k];
            bool kept = valid2 && (acc == 0ull);
            u64 nk = __ballot(kept);
            if (lane == 0) {
                Ksh[(p ^ 1) * 16 + wv] = nk;
                if (nk != kold) chgA[it & 31] = 1;
            }
            __syncthreads();
            finF = p ^ 1;
            if (chgA[it & 31] == 0) break;
            if ((it & 31) == 31) {
                __syncthreads();
                if (tid < 32) chgA[tid] = 0;
                __syncthreads();
            }
        }
        const u64* Kf2 = Ksh + finF * 16;

        // epilogue: rank kept (by index) then zero-score backfill (by index)
        u64 low = (1ull << lane) - 1ull;
        int pc = 0, Kt = 0;
#pragma unroll
        for (int k = 0; k < 16; ++k) {
            u64 kk = Kf2[k];
            u64 lt = (k < wv) ? ~0ull : ((k == wv) ? low : 0ull);
            pc += __popcll(kk & lt);
            Kt += __popcll(kk);
        }
        if (inrF) {
            bool kept = (Kf2[wv] >> lane) & 1ull;
            int row = kept ? pc : (Kt + (tid - pc));
            if (row < 100) {
                u32 v = ~(u32)key;
                u32 a = v >> 7;
                float4 bx = boxes[(size_t)b * NA + a];
                float fsc = kept ? __uint_as_float((u32)(key >> 32)) : 0.0f;
                float* dr = out + (size_t)(b * 100 + row) * 5;
                dr[0] = bx.x; dr[1] = bx.y; dr[2] = bx.z; dr[3] = bx.w; dr[4] = fsc;
                out[(size_t)NB * 100 * 5 + b * 100 + row] = (float)(v & 127u);
            }
        }
    }
}

extern "C" void kernel_launch(void* const* d_in, const int* in_sizes, int n_in,
                              void* d_out, int out_size, void* d_ws, size_t ws_size,
                              hipStream_t stream) {
    const float* cls0 = (const float*)d_in[0];
    const float* cls1 = (const float*)d_in[1];
    const float* cls2 = (const float*)d_in[2];
    const float* box0 = (const float*)d_in[3];
    const float* box1 = (const float*)d_in[4];
    const float* box2 = (const float*)d_in[5];
    float* out = (float*)d_out;

    char* w = (char*)d_ws;
    u64*    f_keys = (u64*)(w);
    float4* boxes  = (float4*)(w + 1075200);

    k_decode<<<dim3(33, NB), 256, 0, stream>>>(cls0, cls1, cls2, box0, box1, box2,
                                               f_keys, boxes);
    k_post<<<NB, 1024, 0, stream>>>(f_keys, boxes, out);
}